// Round 1
// baseline (1377.397 us; speedup 1.0000x reference)
//
#include <hip/hip_runtime.h>
#include <math.h>

typedef __bf16 bf16;
typedef __attribute__((ext_vector_type(4))) __bf16 bf16x4;
typedef __attribute__((ext_vector_type(8))) __bf16 bf16x8;
typedef __attribute__((ext_vector_type(4))) float f32x4;

#define T_STEPS 128
#define B_SZ    256
#define V_SZ    256
#define N_SZ    1024
#define NROWS   (T_STEPS * B_SZ)   // 32768
#define LDSS    72                 // padded LDS stride in elements (64 + 8)

// ---------------- fp32 -> bf16 contiguous convert ----------------
__global__ void k_convert(const float* __restrict__ src, bf16* __restrict__ dst, int n) {
    int i = (blockIdx.x * blockDim.x + threadIdx.x) * 4;
    if (i < n) {
        float4 v = *(const float4*)(src + i);
        bf16x4 o;
        o.x = (bf16)v.x; o.y = (bf16)v.y; o.z = (bf16)v.z; o.w = (bf16)v.w;
        *(bf16x4*)(dst + i) = o;
    }
}

// ---------------- fp32 (R x C) -> bf16 transpose (C x R) ----------------
__global__ void k_transpose_cvt(const float* __restrict__ src, bf16* __restrict__ dst,
                                int R, int C) {
    __shared__ float tile[32][33];
    int c0 = blockIdx.x * 32;
    int r0 = blockIdx.y * 32;
    int tx = threadIdx.x & 31;
    int ty = threadIdx.x >> 5;   // 0..7
#pragma unroll
    for (int i = 0; i < 32; i += 8)
        tile[ty + i][tx] = src[(size_t)(r0 + ty + i) * C + c0 + tx];
    __syncthreads();
#pragma unroll
    for (int i = 0; i < 32; i += 8)
        dst[(size_t)(c0 + ty + i) * R + r0 + tx] = (bf16)tile[tx][ty + i];
}

// ---------------- Xproj: XH[i][n] = bf16( X[i]@Wx[:,n] + bias[n] ) ----------------
// A: Xb (32768 x 256), B: Wxt (1024 x 256) = Wx^T. Tile 64x64, 4 waves 2x2.
__global__ __launch_bounds__(256) void k_xproj(
    const bf16* __restrict__ X, const bf16* __restrict__ Wxt,
    const float* __restrict__ bias, bf16* __restrict__ XH)
{
    __shared__ __align__(16) bf16 As[64 * LDSS];
    __shared__ __align__(16) bf16 Bs[64 * LDSS];
    const int tid  = threadIdx.x;
    const int lane = tid & 63;
    const int w    = tid >> 6;
    const int wm   = (w >> 1) * 32;
    const int wn   = (w & 1) * 32;
    const int quad = lane >> 4;
    const int l15  = lane & 15;
    const int m0 = blockIdx.x * 64;
    const int n0 = blockIdx.y * 64;

    const bf16* Ag = X + (size_t)m0 * V_SZ;
    const bf16* Bg = Wxt + (size_t)n0 * V_SZ;

    f32x4 z = {0.f, 0.f, 0.f, 0.f};
    f32x4 acc00 = z, acc01 = z, acc10 = z, acc11 = z;

    for (int k0 = 0; k0 < V_SZ; k0 += 64) {
        {
            int c = tid, row = c >> 3, col = (c & 7) * 8;
            *(bf16x8*)&As[row * LDSS + col] = *(const bf16x8*)&Ag[(size_t)row * V_SZ + k0 + col];
            *(bf16x8*)&Bs[row * LDSS + col] = *(const bf16x8*)&Bg[(size_t)row * V_SZ + k0 + col];
            c = tid + 256; row = c >> 3; col = (c & 7) * 8;
            *(bf16x8*)&As[row * LDSS + col] = *(const bf16x8*)&Ag[(size_t)row * V_SZ + k0 + col];
            *(bf16x8*)&Bs[row * LDSS + col] = *(const bf16x8*)&Bg[(size_t)row * V_SZ + k0 + col];
        }
        __syncthreads();
#pragma unroll
        for (int kc = 0; kc < 64; kc += 32) {
            bf16x8 a0 = *(const bf16x8*)&As[(wm + l15) * LDSS + kc + quad * 8];
            bf16x8 a1 = *(const bf16x8*)&As[(wm + 16 + l15) * LDSS + kc + quad * 8];
            bf16x8 b0 = *(const bf16x8*)&Bs[(wn + l15) * LDSS + kc + quad * 8];
            bf16x8 b1 = *(const bf16x8*)&Bs[(wn + 16 + l15) * LDSS + kc + quad * 8];
            acc00 = __builtin_amdgcn_mfma_f32_16x16x32_bf16(a0, b0, acc00, 0, 0, 0);
            acc01 = __builtin_amdgcn_mfma_f32_16x16x32_bf16(a0, b1, acc01, 0, 0, 0);
            acc10 = __builtin_amdgcn_mfma_f32_16x16x32_bf16(a1, b0, acc10, 0, 0, 0);
            acc11 = __builtin_amdgcn_mfma_f32_16x16x32_bf16(a1, b1, acc11, 0, 0, 0);
        }
        __syncthreads();
    }
    bf16* Out = XH + (size_t)m0 * N_SZ + n0;
    const f32x4 accs[2][2] = {{acc00, acc01}, {acc10, acc11}};
#pragma unroll
    for (int mi = 0; mi < 2; ++mi)
#pragma unroll
        for (int r = 0; r < 4; ++r) {
            int row = wm + mi * 16 + quad * 4 + r;
#pragma unroll
            for (int ni = 0; ni < 2; ++ni) {
                int col = wn + ni * 16 + l15;
                float pre = accs[mi][ni][r] + bias[n0 + col];
                Out[(size_t)row * N_SZ + col] = (bf16)pre;
            }
        }
}

// ---------------- recurrent step: XH[t] = tanh(XH[t] + XH[t-1] @ Wh) ----------------
// Tile 32x64, grid (8,16)=128 blocks, 4 waves 2x2 (16x32 each).
__global__ __launch_bounds__(256) void k_step(
    const bf16* __restrict__ Wht,   // 1024 x 1024 = Wh^T
    bf16* __restrict__ XH, int t)
{
    __shared__ __align__(16) bf16 As[32 * LDSS];
    __shared__ __align__(16) bf16 Bs[64 * LDSS];
    const int tid  = threadIdx.x;
    const int lane = tid & 63;
    const int w    = tid >> 6;
    const int wm   = (w >> 1) * 16;   // 0 / 16
    const int wn   = (w & 1) * 32;    // 0 / 32
    const int quad = lane >> 4;
    const int l15  = lane & 15;
    const int m0 = blockIdx.x * 32;
    const int n0 = blockIdx.y * 64;

    f32x4 z = {0.f, 0.f, 0.f, 0.f};
    f32x4 acc0 = z, acc1 = z;

    if (t > 0) {
        const bf16* Ag = XH + ((size_t)(t - 1) * B_SZ + m0) * N_SZ;
        const bf16* Bg = Wht + (size_t)n0 * N_SZ;
        for (int k0 = 0; k0 < N_SZ; k0 += 64) {
            {   // A tile: 32 rows x 64 k = 256 chunks of 8
                int row = tid >> 3, col = (tid & 7) * 8;
                *(bf16x8*)&As[row * LDSS + col] = *(const bf16x8*)&Ag[(size_t)row * N_SZ + k0 + col];
            }
            {   // B tile: 64 rows x 64 k = 512 chunks
                int c = tid, row = c >> 3, col = (c & 7) * 8;
                *(bf16x8*)&Bs[row * LDSS + col] = *(const bf16x8*)&Bg[(size_t)row * N_SZ + k0 + col];
                c = tid + 256; row = c >> 3; col = (c & 7) * 8;
                *(bf16x8*)&Bs[row * LDSS + col] = *(const bf16x8*)&Bg[(size_t)row * N_SZ + k0 + col];
            }
            __syncthreads();
#pragma unroll
            for (int kc = 0; kc < 64; kc += 32) {
                bf16x8 a0 = *(const bf16x8*)&As[(wm + l15) * LDSS + kc + quad * 8];
                bf16x8 b0 = *(const bf16x8*)&Bs[(wn + l15) * LDSS + kc + quad * 8];
                bf16x8 b1 = *(const bf16x8*)&Bs[(wn + 16 + l15) * LDSS + kc + quad * 8];
                acc0 = __builtin_amdgcn_mfma_f32_16x16x32_bf16(a0, b0, acc0, 0, 0, 0);
                acc1 = __builtin_amdgcn_mfma_f32_16x16x32_bf16(a0, b1, acc1, 0, 0, 0);
            }
            __syncthreads();
        }
    }
    bf16* Out = XH + ((size_t)t * B_SZ + m0) * N_SZ + n0;
    const f32x4 accs[2] = {acc0, acc1};
#pragma unroll
    for (int r = 0; r < 4; ++r) {
        int row = wm + quad * 4 + r;
#pragma unroll
        for (int ni = 0; ni < 2; ++ni) {
            int col = wn + ni * 16 + l15;
            float pre = accs[ni][r] + (float)Out[(size_t)row * N_SZ + col];
            Out[(size_t)row * N_SZ + col] = (bf16)tanhf(pre);
        }
    }
}

// ---------------- fused logits + log-softmax + loss ----------------
// Block: 64 rows x 256 logits. Wave w: rows w*16..+16, acc over 16 n-tiles.
__global__ __launch_bounds__(256) void k_loss(
    const bf16* __restrict__ XH,
    const bf16* __restrict__ Wot,    // 256 x 1024 = Wout^T
    const float* __restrict__ ob,
    const float* __restrict__ labels,
    float* __restrict__ out)
{
    __shared__ __align__(16) bf16 As[64 * LDSS];
    __shared__ __align__(16) bf16 Bs[256 * LDSS];
    const int tid  = threadIdx.x;
    const int lane = tid & 63;
    const int w    = tid >> 6;
    const int quad = lane >> 4;
    const int l15  = lane & 15;
    const int m0 = blockIdx.x * 64;

    f32x4 z = {0.f, 0.f, 0.f, 0.f};
    f32x4 acc[16];
#pragma unroll
    for (int i = 0; i < 16; ++i) acc[i] = z;

    const bf16* Ag = XH + (size_t)m0 * N_SZ;
    for (int k0 = 0; k0 < N_SZ; k0 += 64) {
        {
            int c = tid, row = c >> 3, col = (c & 7) * 8;
            *(bf16x8*)&As[row * LDSS + col] = *(const bf16x8*)&Ag[(size_t)row * N_SZ + k0 + col];
            c = tid + 256; row = c >> 3; col = (c & 7) * 8;
            *(bf16x8*)&As[row * LDSS + col] = *(const bf16x8*)&Ag[(size_t)row * N_SZ + k0 + col];
        }
#pragma unroll
        for (int c = tid; c < 2048; c += 256) {
            int row = c >> 3, col = (c & 7) * 8;
            *(bf16x8*)&Bs[row * LDSS + col] = *(const bf16x8*)&Wot[(size_t)row * N_SZ + k0 + col];
        }
        __syncthreads();
#pragma unroll
        for (int kc = 0; kc < 64; kc += 32) {
            bf16x8 a = *(const bf16x8*)&As[(w * 16 + l15) * LDSS + kc + quad * 8];
#pragma unroll
            for (int nt = 0; nt < 16; ++nt) {
                bf16x8 b = *(const bf16x8*)&Bs[(nt * 16 + l15) * LDSS + kc + quad * 8];
                acc[nt] = __builtin_amdgcn_mfma_f32_16x16x32_bf16(a, b, acc[nt], 0, 0, 0);
            }
        }
        __syncthreads();
    }

    float obv[16];
#pragma unroll
    for (int nt = 0; nt < 16; ++nt) obv[nt] = ob[nt * 16 + l15];

    float total = 0.f;
#pragma unroll
    for (int r = 0; r < 4; ++r) {
        int row = m0 + w * 16 + quad * 4 + r;
        float vals[16];
        float lmax = -3.0e38f;
#pragma unroll
        for (int nt = 0; nt < 16; ++nt) {
            vals[nt] = acc[nt][r] + obv[nt];
            lmax = fmaxf(lmax, vals[nt]);
        }
#pragma unroll
        for (int s = 1; s < 16; s <<= 1)
            lmax = fmaxf(lmax, __shfl_xor(lmax, s, 64));
        float sume = 0.f, labv = 0.f, labs = 0.f;
        const float* lrow = labels + (size_t)row * V_SZ;
#pragma unroll
        for (int nt = 0; nt < 16; ++nt) {
            sume += __expf(vals[nt] - lmax);
            float lb = lrow[nt * 16 + l15];
            labv += lb * vals[nt];
            labs += lb;
        }
#pragma unroll
        for (int s = 1; s < 16; s <<= 1) {
            sume += __shfl_xor(sume, s, 64);
            labv += __shfl_xor(labv, s, 64);
            labs += __shfl_xor(labs, s, 64);
        }
        float lse = lmax + __logf(sume);
        total += labs * lse - labv;
    }
    if (l15 == 0)
        atomicAdd(out, total * (1.0f / (float)NROWS));
}

extern "C" void kernel_launch(void* const* d_in, const int* in_sizes, int n_in,
                              void* d_out, int out_size, void* d_ws, size_t ws_size,
                              hipStream_t stream)
{
    const float* inputs  = (const float*)d_in[0];
    const float* labels  = (const float*)d_in[1];
    const float* weights = (const float*)d_in[2];
    const float* bias    = (const float*)d_in[3];
    const float* out_w   = (const float*)d_in[4];
    const float* out_b   = (const float*)d_in[5];
    float* out = (float*)d_out;

    char* ws = (char*)d_ws;
    bf16* XH  = (bf16*)ws;  ws += (size_t)NROWS * N_SZ * 2;   // 64 MB, Xproj then H in place
    bf16* Xb  = (bf16*)ws;  ws += (size_t)NROWS * V_SZ * 2;   // 16 MB
    bf16* Wxt = (bf16*)ws;  ws += (size_t)N_SZ * V_SZ * 2;    // 0.5 MB (Wx^T: 1024x256)
    bf16* Wht = (bf16*)ws;  ws += (size_t)N_SZ * N_SZ * 2;    // 2 MB   (Wh^T: 1024x1024)
    bf16* Wot = (bf16*)ws;  ws += (size_t)V_SZ * N_SZ * 2;    // 0.5 MB (Wo^T: 256x1024)

    hipMemsetAsync(out, 0, sizeof(float), stream);

    k_convert<<<dim3(NROWS * V_SZ / 1024), 256, 0, stream>>>(inputs, Xb, NROWS * V_SZ);
    k_transpose_cvt<<<dim3(N_SZ / 32, V_SZ / 32), 256, 0, stream>>>(weights, Wxt, V_SZ, N_SZ);
    k_transpose_cvt<<<dim3(N_SZ / 32, N_SZ / 32), 256, 0, stream>>>(
        weights + (size_t)V_SZ * N_SZ, Wht, N_SZ, N_SZ);
    k_transpose_cvt<<<dim3(V_SZ / 32, N_SZ / 32), 256, 0, stream>>>(out_w, Wot, N_SZ, V_SZ);

    k_xproj<<<dim3(NROWS / 64, N_SZ / 64), 256, 0, stream>>>(Xb, Wxt, bias, XH);

    for (int t = 0; t < T_STEPS; ++t)
        k_step<<<dim3(B_SZ / 32, N_SZ / 64), 256, 0, stream>>>(Wht, XH, t);

    k_loss<<<dim3(NROWS / 64), 256, 0, stream>>>(XH, Wot, out_b, labels, out);
}